// Round 4
// baseline (127351.843 us; speedup 1.0000x reference)
//
#include <hip/hip_runtime.h>
#include <hip/hip_cooperative_groups.h>

#define T_ 512
#define B_ 256
#define H_ 256
#define DIN_ 64

namespace cg = cooperative_groups;

typedef __attribute__((ext_vector_type(8))) short short8;
typedef __attribute__((ext_vector_type(4))) float f32x4;
typedef __attribute__((ext_vector_type(4))) unsigned int u32x4;

__device__ __forceinline__ unsigned short f2bf(float f) {
  unsigned u = __float_as_uint(f);
  u += 0x7FFFu + ((u >> 16) & 1u);   // RNE
  return (unsigned short)(u >> 16);
}
__device__ __forceinline__ float bf2f(unsigned short s) {
  return __uint_as_float(((unsigned)s) << 16);
}
__device__ __forceinline__ float sigm(float x) { return 1.0f / (1.0f + __expf(-x)); }
__device__ __forceinline__ float tanh_(float x) {
  float xx = fminf(fmaxf(x, -30.0f), 30.0f);
  float e = __expf(2.0f * xx);
  return (e - 1.0f) / (e + 1.0f);
}

__device__ __forceinline__ bool tags_ok(u32x4 a, u32x4 b, u32x4 c, u32x4 d,
                                        unsigned w) {
  unsigned m = (a.x >> 16) ^ w; m |= (a.y >> 16) ^ w;
  m |= (a.z >> 16) ^ w;         m |= (a.w >> 16) ^ w;
  m |= (b.x >> 16) ^ w;         m |= (b.y >> 16) ^ w;
  m |= (b.z >> 16) ^ w;         m |= (b.w >> 16) ^ w;
  m |= (c.x >> 16) ^ w;         m |= (c.y >> 16) ^ w;
  m |= (c.z >> 16) ^ w;         m |= (c.w >> 16) ^ w;
  m |= (d.x >> 16) ^ w;         m |= (d.y >> 16) ^ w;
  m |= (d.z >> 16) ^ w;         m |= (d.w >> 16) ^ w;
  return m == 0;
}

// h exchange element = (step_tag << 16) | bf16(h). Self-validating: the load
// IS the poll. DOUBLE-BUFFERED by step parity (R3 lacked this -> clobber ->
// permanent tag mismatch -> hang). With 2 buffers: producer stores s+1 only
// after acquiring all of s, which needs all peers to have stored s, which
// needs all peers done reading s-1 => no live slot is ever clobbered.
// ws re-poisoned to 0xAA each launch -> initial tag 0xAAAA never matches.
//
// Group formation: wgs claim a rank on their XCD (HW_REG_XCC_ID), grid.sync(),
// then deterministically form 16 groups of 16. Same-XCD ("local") groups
// exchange h through their XCD L2: plain stores (write-through L1) + sc0
// loads (bypass L1, hit L2). Mixed groups / sc0 failure fall back to sc1
// agent atomics (LLC) — staleness only causes retries, never wrong data.
__global__ __launch_bounds__(256) void lstm_kern(
    const float* __restrict__ xin, const float* __restrict__ h0f,
    const float* __restrict__ c0f, const float* __restrict__ Wih,
    const float* __restrict__ Whh, const float* __restrict__ bias,
    const float* __restrict__ Wout, const float* __restrict__ bout,
    float* __restrict__ out, unsigned* hbuf32, int* claim)
{
  const int tid = threadIdx.x;
  const int wv  = tid >> 6;   // wave = gate type (i,f,g,o)
  const int ln  = tid & 63;
  const int colB = ln & 15;   // MFMA n / A-row m
  const int krow = ln >> 4;   // MFMA k-quad

  __shared__ unsigned short h_s[16 * 264];  // 16 rows x 256 bf16, pitch 264
  __shared__ unsigned short x_s[16 * 72];   // 16 rows x 64  bf16, pitch 72
  __shared__ float gbuf[4 * 16 * 17];       // [gate][row][col] padded
  __shared__ int s_tmp[3];

  // ---- phase A: claim a rank on my XCD ----
  if (tid == 0) {
    unsigned xid;
    asm volatile("s_getreg_b32 %0, hwreg(HW_REG_XCC_ID)" : "=s"(xid));
    xid &= 7u;
    int rank = atomicAdd(&claim[xid], 1);
    s_tmp[0] = (int)xid; s_tmp[1] = rank;
  }
  cg::this_grid().sync();

  // ---- phase B: deterministic group assignment from final counts ----
  if (tid == 0) {
    int xcd = s_tmp[0], rank = s_tmp[1];
    int cnt[8], lg[8];
    #pragma unroll
    for (int i = 0; i < 8; ++i) {
      cnt[i] = __hip_atomic_load(&claim[i], __ATOMIC_RELAXED,
                                 __HIP_MEMORY_SCOPE_AGENT);
      lg[i] = cnt[i] >> 4; if (lg[i] > 2) lg[i] = 2;
    }
    int Ltot = 0, Lbase = 0, leftb = 0;
    #pragma unroll
    for (int i = 0; i < 8; ++i) Ltot += lg[i];
    for (int i = 0; i < xcd; ++i) { Lbase += lg[i]; leftb += cnt[i] - lg[i] * 16; }
    int gbv, gcv, loc;
    if (rank < lg[xcd] * 16) {
      gbv = Lbase + (rank >> 4); gcv = rank & 15; loc = 1;
    } else {
      int li = leftb + (rank - lg[xcd] * 16);
      gbv = Ltot + (li >> 4); gcv = li & 15; loc = 0;
    }
    s_tmp[0] = gbv; s_tmp[1] = gcv; s_tmp[2] = loc;
  }
  __syncthreads();
  const int gb = s_tmp[0], gc = s_tmp[1], local = s_tmp[2];

  // ---- load W fragments (B-operand layout) ----
  const int j = wv * H_ + gc * 16 + colB;   // row in [0,4H)
  short8 bh[8], bx[2];
  #pragma unroll
  for (int kc = 0; kc < 8; ++kc) {
    const float* p = Whh + j * H_ + kc * 32 + krow * 8;
    short8 f;
    #pragma unroll
    for (int i = 0; i < 8; ++i) f[i] = (short)f2bf(p[i]);
    bh[kc] = f;
  }
  #pragma unroll
  for (int kc = 0; kc < 2; ++kc) {
    const float* p = Wih + j * DIN_ + kc * 32 + krow * 8;
    short8 f;
    #pragma unroll
    for (int i = 0; i < 8; ++i) f[i] = (short)f2bf(p[i]);
    bx[kc] = f;
  }
  const float bval = bias[j];

  // elementwise mapping: thread owns (row er, h-col ec) of this wg's slice
  const int er = tid >> 4, ec = tid & 15;
  const int grow = gb * 16 + er;
  float c_val = c0f[grow * H_ + gc * 16 + ec];
  float h_val = 0.0f;

  // h-exchange region: hbuf32[2 parity][16 groups][16 rows][256 cols] dwords
  const int hr = tid >> 4;            // consumer row
  const int hcb = (tid & 15) * 16;    // consumer col base (16 dwords)
  const unsigned* ldp_base = hbuf32 + gb * 4096 + hr * 256 + hcb;
  unsigned* stp_base = hbuf32 + gb * 4096 + er * 256 + gc * 16 + ec;

  for (int s = 1; s <= T_; ++s) {
    // ---- stage x_{s-1} -> LDS bf16 ----
    #pragma unroll
    for (int it = 0; it < 4; ++it) {
      int e = tid + it * 256;
      int r = e >> 6, d = e & 63;
      float v = xin[((gb * 16 + r) * T_ + (s - 1)) * DIN_ + d];
      x_s[r * 72 + d] = f2bf(v);
    }

    // ---- acquire h^(s-1): tag-validated loads (the load IS the poll) ----
    if (s == 1) {
      #pragma unroll
      for (int it = 0; it < 4; ++it) {
        int e4 = tid + it * 256;
        int r = e4 >> 6, c4 = e4 & 63;
        const float4* p = (const float4*)(h0f + (gb * 16 + r) * H_) + c4;
        float4 v = *p;
        unsigned short* q = &h_s[r * 264 + c4 * 4];
        q[0] = f2bf(v.x); q[1] = f2bf(v.y); q[2] = f2bf(v.z); q[3] = f2bf(v.w);
      }
    } else {
      const unsigned want = (unsigned)(s - 1);
      const unsigned* ldp = ldp_base + (((s - 1) & 1) << 16);  // parity buffer
      u32x4 va, vb, vc, vd;
      bool ok = false;
      if (local) {
        for (int t = 0; t < 1024; ++t) {
          asm volatile(
              "global_load_dwordx4 %0, %4, off sc0\n\t"
              "global_load_dwordx4 %1, %4, off offset:16 sc0\n\t"
              "global_load_dwordx4 %2, %4, off offset:32 sc0\n\t"
              "global_load_dwordx4 %3, %4, off offset:48 sc0\n\t"
              "s_waitcnt vmcnt(0)"
              : "=v"(va), "=v"(vb), "=v"(vc), "=v"(vd)
              : "v"(ldp) : "memory");
          if (tags_ok(va, vb, vc, vd, want)) { ok = true; break; }
        }
      }
      if (!ok) {  // mixed group, or local path didn't deliver: LLC path
        int tries = 0;
        while (true) {
          #pragma unroll
          for (int i = 0; i < 4; ++i) {
            va[i] = __hip_atomic_load(ldp + i,      __ATOMIC_RELAXED, __HIP_MEMORY_SCOPE_AGENT);
            vb[i] = __hip_atomic_load(ldp + 4 + i,  __ATOMIC_RELAXED, __HIP_MEMORY_SCOPE_AGENT);
            vc[i] = __hip_atomic_load(ldp + 8 + i,  __ATOMIC_RELAXED, __HIP_MEMORY_SCOPE_AGENT);
            vd[i] = __hip_atomic_load(ldp + 12 + i, __ATOMIC_RELAXED, __HIP_MEMORY_SCOPE_AGENT);
          }
          if (tags_ok(va, vb, vc, vd, want)) break;
          if (++tries > (1 << 18)) break;   // hang guard (unreachable now)
        }
      }
      // pack bf16 payloads -> LDS
      unsigned* q32 = (unsigned*)&h_s[hr * 264 + hcb];
      q32[0] = (va.x & 0xFFFFu) | (va.y << 16);
      q32[1] = (va.z & 0xFFFFu) | (va.w << 16);
      q32[2] = (vb.x & 0xFFFFu) | (vb.y << 16);
      q32[3] = (vb.z & 0xFFFFu) | (vb.w << 16);
      q32[4] = (vc.x & 0xFFFFu) | (vc.y << 16);
      q32[5] = (vc.z & 0xFFFFu) | (vc.w << 16);
      q32[6] = (vd.x & 0xFFFFu) | (vd.y << 16);
      q32[7] = (vd.z & 0xFFFFu) | (vd.w << 16);
    }
    __syncthreads();   // (B) x_s + h_s staged

    // ---- gates tile: D[batch m][gate col n], K = 64 (x) + 256 (h) ----
    f32x4 acc = {0.f, 0.f, 0.f, 0.f};
    #pragma unroll
    for (int kc = 0; kc < 2; ++kc) {
      short8 a = *(const short8*)&x_s[colB * 72 + kc * 32 + krow * 8];
      acc = __builtin_amdgcn_mfma_f32_16x16x32_bf16(a, bx[kc], acc, 0, 0, 0);
    }
    #pragma unroll
    for (int kc = 0; kc < 8; ++kc) {
      short8 a = *(const short8*)&h_s[colB * 264 + kc * 32 + krow * 8];
      acc = __builtin_amdgcn_mfma_f32_16x16x32_bf16(a, bh[kc], acc, 0, 0, 0);
    }
    #pragma unroll
    for (int i = 0; i < 4; ++i)   // D layout: col=lane&15, row=quad*4+i
      gbuf[wv * 272 + (krow * 4 + i) * 17 + colB] = acc[i] + bval;
    __syncthreads();   // (C)

    // ---- elementwise LSTM cell update ----
    float gi = gbuf[0 * 272 + er * 17 + ec];
    float gf = gbuf[1 * 272 + er * 17 + ec];
    float gg = gbuf[2 * 272 + er * 17 + ec];
    float go = gbuf[3 * 272 + er * 17 + ec];
    c_val = sigm(gf) * c_val + sigm(gi) * tanh_(gg);
    h_val = sigm(go) * tanh_(c_val);

    // ---- publish: fire-and-forget tagged store into parity buffer ----
    unsigned pk = ((unsigned)s << 16) | (unsigned)f2bf(h_val);
    unsigned* stp = stp_base + ((s & 1) << 16);
    if (local)
      __hip_atomic_store(stp, pk, __ATOMIC_RELAXED, __HIP_MEMORY_SCOPE_WORKGROUP);
    else
      __hip_atomic_store(stp, pk, __ATOMIC_RELAXED, __HIP_MEMORY_SCOPE_AGENT);
  }

  // ---- outputs: rnn_outputs | logits | h | c ----
  const int gj = gc * 16 + ec;
  out[grow * H_ + gj] = h_val;                 // out0: rnn_outputs
  out[67584 + grow * H_ + gj] = h_val;         // out2: h
  out[133120 + grow * H_ + gj] = c_val;        // out3: c

  if (gc == 0) {  // logits for this batch group: need full h^T rows
    const unsigned want = (unsigned)T_;
    const unsigned* ldp = ldp_base + ((T_ & 1) << 16);
    u32x4 va, vb, vc, vd;
    bool ok = false;
    if (local) {
      for (int t = 0; t < 1024; ++t) {
        asm volatile(
            "global_load_dwordx4 %0, %4, off sc0\n\t"
            "global_load_dwordx4 %1, %4, off offset:16 sc0\n\t"
            "global_load_dwordx4 %2, %4, off offset:32 sc0\n\t"
            "global_load_dwordx4 %3, %4, off offset:48 sc0\n\t"
            "s_waitcnt vmcnt(0)"
            : "=v"(va), "=v"(vb), "=v"(vc), "=v"(vd)
            : "v"(ldp) : "memory");
        if (tags_ok(va, vb, vc, vd, want)) { ok = true; break; }
      }
    }
    if (!ok) {
      int tries = 0;
      while (true) {
        #pragma unroll
        for (int i = 0; i < 4; ++i) {
          va[i] = __hip_atomic_load(ldp + i,      __ATOMIC_RELAXED, __HIP_MEMORY_SCOPE_AGENT);
          vb[i] = __hip_atomic_load(ldp + 4 + i,  __ATOMIC_RELAXED, __HIP_MEMORY_SCOPE_AGENT);
          vc[i] = __hip_atomic_load(ldp + 8 + i,  __ATOMIC_RELAXED, __HIP_MEMORY_SCOPE_AGENT);
          vd[i] = __hip_atomic_load(ldp + 12 + i, __ATOMIC_RELAXED, __HIP_MEMORY_SCOPE_AGENT);
        }
        if (tags_ok(va, vb, vc, vd, want)) break;
        if (++tries > (1 << 18)) break;
      }
    }
    unsigned* q32 = (unsigned*)&h_s[hr * 264 + hcb];
    q32[0] = (va.x & 0xFFFFu) | (va.y << 16);
    q32[1] = (va.z & 0xFFFFu) | (va.w << 16);
    q32[2] = (vb.x & 0xFFFFu) | (vb.y << 16);
    q32[3] = (vb.z & 0xFFFFu) | (vb.w << 16);
    q32[4] = (vc.x & 0xFFFFu) | (vc.y << 16);
    q32[5] = (vc.z & 0xFFFFu) | (vc.w << 16);
    q32[6] = (vd.x & 0xFFFFu) | (vd.y << 16);
    q32[7] = (vd.z & 0xFFFFu) | (vd.w << 16);
    __syncthreads();
    if (tid < 128) {
      int r = tid >> 3, o = tid & 7;
      float a = bout[o];
      for (int k = 0; k < H_; ++k)
        a = fmaf(bf2f(h_s[r * 264 + k]), Wout[o * H_ + k], a);
      out[65536 + (gb * 16 + r) * 8 + o] = a;   // out1: logits
    }
  }
}

extern "C" void kernel_launch(void* const* d_in, const int* in_sizes, int n_in,
                              void* d_out, int out_size, void* d_ws, size_t ws_size,
                              hipStream_t stream) {
  const float* xin  = (const float*)d_in[0];
  const float* h0f  = (const float*)d_in[1];
  const float* c0f  = (const float*)d_in[2];
  const float* Wih  = (const float*)d_in[3];
  const float* Whh  = (const float*)d_in[4];
  const float* bias = (const float*)d_in[5];
  const float* Wout = (const float*)d_in[6];
  const float* bout = (const float*)d_in[7];
  float* out = (float*)d_out;

  // ws: hbuf32[2][16][16][256] dwords (512 KiB) | claim[8]
  unsigned* hbuf32 = (unsigned*)d_ws;
  int* claim = (int*)((char*)d_ws + 2 * 16 * 16 * 256 * 4);
  hipMemsetAsync(claim, 0, 8 * sizeof(int), stream);

  void* args[] = {&xin, &h0f, &c0f, &Wih, &Whh, &bias, &Wout, &bout,
                  &out, &hbuf32, &claim};
  hipLaunchCooperativeKernel((void*)lstm_kern, dim3(256), dim3(256),
                             args, 0, stream);
}

// Round 5
// 1175.804 us; speedup vs baseline: 108.3104x; 108.3104x over previous
//
#include <hip/hip_runtime.h>

#define T_ 512
#define B_ 256
#define H_ 256
#define DIN_ 64

typedef __attribute__((ext_vector_type(8))) short short8;
typedef __attribute__((ext_vector_type(4))) float f32x4;
typedef __attribute__((ext_vector_type(4))) unsigned int u32x4;

__device__ __forceinline__ unsigned short f2bf(float f) {
  unsigned u = __float_as_uint(f);
  u += 0x7FFFu + ((u >> 16) & 1u);   // RNE
  return (unsigned short)(u >> 16);
}
__device__ __forceinline__ float bf2f(unsigned short s) {
  return __uint_as_float(((unsigned)s) << 16);
}
__device__ __forceinline__ float sigm(float x) { return 1.0f / (1.0f + __expf(-x)); }
__device__ __forceinline__ float tanh_(float x) {
  float xx = fminf(fmaxf(x, -30.0f), 30.0f);
  float e = __expf(2.0f * xx);
  return (e - 1.0f) / (e + 1.0f);
}

// 4x dwordx4 load with sc1 (agent scope): bypasses L1 (and non-agent-coherent
// L2) -> reads LLC-fresh data. This is the instruction class R2 proved works;
// R4's sc0 variant hit stale L1 forever (the 46x regression).
__device__ __forceinline__ void load16_sc1(const unsigned* p, u32x4& a,
                                           u32x4& b, u32x4& c, u32x4& d) {
  asm volatile(
      "global_load_dwordx4 %0, %4, off sc1\n\t"
      "global_load_dwordx4 %1, %4, off offset:16 sc1\n\t"
      "global_load_dwordx4 %2, %4, off offset:32 sc1\n\t"
      "global_load_dwordx4 %3, %4, off offset:48 sc1\n\t"
      "s_waitcnt vmcnt(0)"
      : "=v"(a), "=v"(b), "=v"(c), "=v"(d)
      : "v"(p) : "memory");
}

__device__ __forceinline__ bool tags_ok(u32x4 a, u32x4 b, u32x4 c, u32x4 d,
                                        unsigned w) {
  unsigned m = (a.x >> 16) ^ w; m |= (a.y >> 16) ^ w;
  m |= (a.z >> 16) ^ w;         m |= (a.w >> 16) ^ w;
  m |= (b.x >> 16) ^ w;         m |= (b.y >> 16) ^ w;
  m |= (b.z >> 16) ^ w;         m |= (b.w >> 16) ^ w;
  m |= (c.x >> 16) ^ w;         m |= (c.y >> 16) ^ w;
  m |= (c.z >> 16) ^ w;         m |= (c.w >> 16) ^ w;
  m |= (d.x >> 16) ^ w;         m |= (d.y >> 16) ^ w;
  m |= (d.z >> 16) ^ w;         m |= (d.w >> 16) ^ w;
  return m == 0;
}

// Grid: 256 wgs x 256 threads. wg = gb*16 + gc (gb: 16 batch rows,
// gc: 16 h-cols -> 64 gate cols). Wave w computes gate type w (i,f,g,o) as
// one 16x16 MFMA tile; W_ih/W_hh fragments VGPR-resident for the whole run.
//
// h exchange element = (step_tag << 16) | bf16(h); parity double-buffered.
// Safety: wg X stores tag s+1 (clobbering its s-1 entry) only after X
// acquired ALL of s; each peer published s only after fully acquiring s-1;
// so every reader of the s-1 entry finished before the clobber. The load IS
// the poll: no flag array, no store-drain/flag/poll serialization, and
// stores are fire-and-forget (no barrier between cell update and store).
// ws re-poisoned to 0xAA each launch -> initial tag 0xAAAA never matches.
__global__ __launch_bounds__(256) void lstm_kern(
    const float* __restrict__ xin, const float* __restrict__ h0f,
    const float* __restrict__ c0f, const float* __restrict__ Wih,
    const float* __restrict__ Whh, const float* __restrict__ bias,
    const float* __restrict__ Wout, const float* __restrict__ bout,
    float* __restrict__ out, unsigned* hbuf32)
{
  const int tid = threadIdx.x;
  const int gb  = blockIdx.x >> 4;
  const int gc  = blockIdx.x & 15;
  const int wv  = tid >> 6;   // wave = gate type (i,f,g,o)
  const int ln  = tid & 63;
  const int colB = ln & 15;   // MFMA n / A-row m
  const int krow = ln >> 4;   // MFMA k-quad

  __shared__ unsigned short h_s[16 * 264];  // 16 rows x 256 bf16, pitch 264
  __shared__ unsigned short x_s[16 * 72];   // 16 rows x 64  bf16, pitch 72
  __shared__ float gbuf[4 * 16 * 17];       // [gate][row][col] padded

  // ---- load W fragments (B-operand layout: lane holds W[j][k=krow*8+i]) ----
  const int j = wv * H_ + gc * 16 + colB;   // row in [0,4H)
  short8 bh[8], bx[2];
  #pragma unroll
  for (int kc = 0; kc < 8; ++kc) {
    const float* p = Whh + j * H_ + kc * 32 + krow * 8;
    short8 f;
    #pragma unroll
    for (int i = 0; i < 8; ++i) f[i] = (short)f2bf(p[i]);
    bh[kc] = f;
  }
  #pragma unroll
  for (int kc = 0; kc < 2; ++kc) {
    const float* p = Wih + j * DIN_ + kc * 32 + krow * 8;
    short8 f;
    #pragma unroll
    for (int i = 0; i < 8; ++i) f[i] = (short)f2bf(p[i]);
    bx[kc] = f;
  }
  const float bval = bias[j];

  // elementwise mapping: thread owns (row er, h-col ec) of this wg's slice
  const int er = tid >> 4, ec = tid & 15;
  const int grow = gb * 16 + er;
  float c_val = c0f[grow * H_ + gc * 16 + ec];
  float h_val = 0.0f;

  // hbuf32[2 parity][16 groups][16 rows][256 cols] dwords
  const int hr = tid >> 4;            // consumer row
  const int hcb = (tid & 15) * 16;    // consumer col base (16 dwords)
  const unsigned* ldp_base = hbuf32 + gb * 4096 + hr * 256 + hcb;
  unsigned* stp_base = hbuf32 + gb * 4096 + er * 256 + gc * 16 + ec;

  for (int s = 1; s <= T_; ++s) {
    // ---- stage x_{s-1} -> LDS bf16 (float4: 1 load/thread) ----
    {
      int r = tid >> 4, d4 = (tid & 15) * 4;
      float4 v = *(const float4*)(xin + ((gb * 16 + r) * T_ + (s - 1)) * DIN_ + d4);
      unsigned short* q = &x_s[r * 72 + d4];
      q[0] = f2bf(v.x); q[1] = f2bf(v.y); q[2] = f2bf(v.z); q[3] = f2bf(v.w);
    }

    // ---- acquire h^(s-1): tag-validated sc1 loads (the load IS the poll) ----
    if (s == 1) {
      #pragma unroll
      for (int it = 0; it < 4; ++it) {
        int e4 = tid + it * 256;
        int r = e4 >> 6, c4 = e4 & 63;
        const float4* p = (const float4*)(h0f + (gb * 16 + r) * H_) + c4;
        float4 v = *p;
        unsigned short* q = &h_s[r * 264 + c4 * 4];
        q[0] = f2bf(v.x); q[1] = f2bf(v.y); q[2] = f2bf(v.z); q[3] = f2bf(v.w);
      }
    } else {
      const unsigned want = (unsigned)(s - 1);
      const unsigned* ldp = ldp_base + (((s - 1) & 1) << 16);  // parity buffer
      u32x4 va, vb, vc, vd;
      int tries = 0;
      do {
        load16_sc1(ldp, va, vb, vc, vd);
        if (tags_ok(va, vb, vc, vd, want)) break;
      } while (++tries < (1 << 18));   // hang guard (unreachable per invariant)
      unsigned* q32 = (unsigned*)&h_s[hr * 264 + hcb];
      q32[0] = (va.x & 0xFFFFu) | (va.y << 16);
      q32[1] = (va.z & 0xFFFFu) | (va.w << 16);
      q32[2] = (vb.x & 0xFFFFu) | (vb.y << 16);
      q32[3] = (vb.z & 0xFFFFu) | (vb.w << 16);
      q32[4] = (vc.x & 0xFFFFu) | (vc.y << 16);
      q32[5] = (vc.z & 0xFFFFu) | (vc.w << 16);
      q32[6] = (vd.x & 0xFFFFu) | (vd.y << 16);
      q32[7] = (vd.z & 0xFFFFu) | (vd.w << 16);
    }
    __syncthreads();   // (B) x_s + h_s staged

    // ---- gates tile: D[batch m][gate col n], K = 64 (x) + 256 (h) ----
    f32x4 acc = {0.f, 0.f, 0.f, 0.f};
    #pragma unroll
    for (int kc = 0; kc < 2; ++kc) {
      short8 a = *(const short8*)&x_s[colB * 72 + kc * 32 + krow * 8];
      acc = __builtin_amdgcn_mfma_f32_16x16x32_bf16(a, bx[kc], acc, 0, 0, 0);
    }
    #pragma unroll
    for (int kc = 0; kc < 8; ++kc) {
      short8 a = *(const short8*)&h_s[colB * 264 + kc * 32 + krow * 8];
      acc = __builtin_amdgcn_mfma_f32_16x16x32_bf16(a, bh[kc], acc, 0, 0, 0);
    }
    #pragma unroll
    for (int i = 0; i < 4; ++i)   // D layout: col=lane&15, row=quad*4+i
      gbuf[wv * 272 + (krow * 4 + i) * 17 + colB] = acc[i] + bval;
    __syncthreads();   // (C)

    // ---- elementwise LSTM cell update ----
    float gi = gbuf[0 * 272 + er * 17 + ec];
    float gf = gbuf[1 * 272 + er * 17 + ec];
    float gg = gbuf[2 * 272 + er * 17 + ec];
    float go = gbuf[3 * 272 + er * 17 + ec];
    c_val = sigm(gf) * c_val + sigm(gi) * tanh_(gg);
    h_val = sigm(go) * tanh_(c_val);

    // ---- publish: fire-and-forget tagged sc1 store into parity buffer ----
    unsigned pk = ((unsigned)s << 16) | (unsigned)f2bf(h_val);
    __hip_atomic_store(stp_base + ((s & 1) << 16), pk,
                       __ATOMIC_RELAXED, __HIP_MEMORY_SCOPE_AGENT);
  }

  // ---- outputs: rnn_outputs | logits | h | c ----
  const int gj = gc * 16 + ec;
  out[grow * H_ + gj] = h_val;                 // out0: rnn_outputs
  out[67584 + grow * H_ + gj] = h_val;         // out2: h   (65536+2048)
  out[133120 + grow * H_ + gj] = c_val;        // out3: c

  if (gc == 0) {  // logits for this batch group: need full h^T rows
    const unsigned want = (unsigned)T_;
    const unsigned* ldp = ldp_base + ((T_ & 1) << 16);
    u32x4 va, vb, vc, vd;
    int tries = 0;
    do {
      load16_sc1(ldp, va, vb, vc, vd);
      if (tags_ok(va, vb, vc, vd, want)) break;
    } while (++tries < (1 << 18));
    unsigned* q32 = (unsigned*)&h_s[hr * 264 + hcb];
    q32[0] = (va.x & 0xFFFFu) | (va.y << 16);
    q32[1] = (va.z & 0xFFFFu) | (va.w << 16);
    q32[2] = (vb.x & 0xFFFFu) | (vb.y << 16);
    q32[3] = (vb.z & 0xFFFFu) | (vb.w << 16);
    q32[4] = (vc.x & 0xFFFFu) | (vc.y << 16);
    q32[5] = (vc.z & 0xFFFFu) | (vc.w << 16);
    q32[6] = (vd.x & 0xFFFFu) | (vd.y << 16);
    q32[7] = (vd.z & 0xFFFFu) | (vd.w << 16);
    __syncthreads();
    if (tid < 128) {
      int r = tid >> 3, o = tid & 7;
      float a = bout[o];
      for (int k = 0; k < H_; ++k)
        a = fmaf(bf2f(h_s[r * 264 + k]), Wout[o * H_ + k], a);
      out[65536 + (gb * 16 + r) * 8 + o] = a;   // out1: logits
    }
  }
}

extern "C" void kernel_launch(void* const* d_in, const int* in_sizes, int n_in,
                              void* d_out, int out_size, void* d_ws, size_t ws_size,
                              hipStream_t stream) {
  const float* xin  = (const float*)d_in[0];
  const float* h0f  = (const float*)d_in[1];
  const float* c0f  = (const float*)d_in[2];
  const float* Wih  = (const float*)d_in[3];
  const float* Whh  = (const float*)d_in[4];
  const float* bias = (const float*)d_in[5];
  const float* Wout = (const float*)d_in[6];
  const float* bout = (const float*)d_in[7];
  float* out = (float*)d_out;

  // ws: hbuf32[2][16][16][256] dwords (512 KiB)
  unsigned* hbuf32 = (unsigned*)d_ws;

  void* args[] = {&xin, &h0f, &c0f, &Wih, &Whh, &bias, &Wout, &bout,
                  &out, &hbuf32};
  hipLaunchCooperativeKernel((void*)lstm_kern, dim3(256), dim3(256),
                             args, 0, stream);
}